// Round 1
// baseline (123.775 us; speedup 1.0000x reference)
//
#include <hip/hip_runtime.h>
#include <hip/hip_bf16.h>
#include <math.h>

#define N_NODES 1024
#define T_DIM 8

typedef __bf16 bf16x8 __attribute__((ext_vector_type(8)));
typedef float  f32x4  __attribute__((ext_vector_type(4)));

__device__ __forceinline__ float readlane_f(float v, int l) {
    return __uint_as_float(__builtin_amdgcn_readlane(__float_as_uint(v), l));
}

// ---- Kernel A: h = inp@W ; s1,s2 ; hF = (h*mask_j) in B-frag-ordered tiles --
// hF tile (bt,jt) = 8 chunks of 1KB; chunk c=kc*4+nc, lane l, m 0..7 holds
// h[o = nc*16 + (l&15)][j = jt*64 + (l>>4)*8 + kc*32 + m] * mask_j.
// mask_j folded here (hF only feeds PV; softmax denominator is unmasked).
// Block remap: XCD = linear%8 = t, so hF/s1/s2 for bt land in the same
// XCD-L2 that kernel B's readers (also mapped XCD=t) will hit.
__global__ __launch_bounds__(256) void gat_h_kernel(
    const float* __restrict__ inp, const float* __restrict__ W,
    const float* __restrict__ a, const float* __restrict__ att_mask,
    __bf16* __restrict__ hF, float* __restrict__ s1w, float* __restrict__ s2w)
{
    __shared__ float Wl[64 * 64];
    __shared__ float xl[64 * 64];
    __shared__ __bf16 htl[64 * 72];   // [o][j], stride 72

    const int tid  = threadIdx.x;
    const int blk  = blockIdx.x;
    const int t    = blk & 7;         // XCD id
    const int r_   = blk >> 3;        // 0..63
    const int b    = r_ & 3;
    const int nt   = r_ >> 2;         // j-tile 0..15
    const int bt   = b * 8 + t;
    const int n0   = nt * 64;
    const int lane = tid & 63;        // = o in compute phase
    const int wave = tid >> 6;

    const float4* W4  = (const float4*)W;
    float4*       Wl4 = (float4*)Wl;
    const float4* x4  = (const float4*)(inp + (size_t)(bt * N_NODES + n0) * 64);
    float4*       xl4 = (float4*)xl;
#pragma unroll
    for (int k = 0; k < 4; ++k) {
        Wl4[tid + k * 256] = W4[tid + k * 256];
        xl4[tid + k * 256] = x4[tid + k * 256];
    }
    const float a1 = a[lane];
    const float a2 = a[64 + lane];
    __syncthreads();

#pragma unroll 1
    for (int rg = 0; rg < 16; rg += 4) {
        float xr[4], acc[4];
#pragma unroll
        for (int q = 0; q < 4; ++q) {
            xr[q]  = xl[(wave * 16 + rg + q) * 64 + lane];
            acc[q] = 0.f;
        }
#pragma unroll
        for (int f = 0; f < 64; ++f) {
            float w = Wl[f * 64 + lane];
#pragma unroll
            for (int q = 0; q < 4; ++q)
                acc[q] = fmaf(readlane_f(xr[q], f), w, acc[q]);
        }
#pragma unroll
        for (int q = 0; q < 4; ++q) {
            const int r = wave * 16 + rg + q;   // local j
            float v1 = acc[q] * a1, v2 = acc[q] * a2;
#pragma unroll
            for (int off = 32; off; off >>= 1) {
                v1 += __shfl_xor(v1, off, 64);
                v2 += __shfl_xor(v2, off, 64);
            }
            if (lane == 0) {
                s1w[bt * N_NODES + n0 + r] = v1;
                s2w[bt * N_NODES + n0 + r] = v2;
            }
            const float mjr = att_mask[((size_t)b * N_NODES + n0 + r) * T_DIM + t];
            htl[lane * 72 + r] = (__bf16)(acc[q] * mjr);   // [o][j]
        }
    }
    __syncthreads();

    // hF write: B-frag-ordered chunks (validated r10-r13)
    {
        const int l  = tid & 63;
        const int w  = tid >> 6;
        __bf16* tbase = hF + (size_t)(bt * 16 + nt) * 4096;
#pragma unroll
        for (int cc = 0; cc < 2; ++cc) {
            const int c  = w + cc * 4;       // chunk = kc*4 + nc
            const int nc = c & 3;
            const int kc = c >> 2;
            bf16x8 v = *(const bf16x8*)&htl[(nc * 16 + (l & 15)) * 72
                                            + (l >> 4) * 8 + kc * 32];
            *(bf16x8*)(tbase + (c * 64 + l) * 8) = v;
        }
    }
}

// ---- Kernel B: one-wave flash GAT — r13 body + 2-deep adj pipeline ----------
// 2048 blocks x 64 thr, 1D grid, XCD-local remap: XCD = blk%8 = t.
// All 256 blocks of a given t (4 b's x 64 itiles) run on one XCD, so:
//   - adj[t] (4MB) re-reads across b are L2 hits (b-siblings are adjacent
//     dispatch slots -> time-aligned);
//   - each bt's hF tile set (128KB, 64-way itile reuse) is L2-resident and
//     was written by the same XCD in kernel A.
// Lockstep j-sweep (no per-itile phase stagger): hot adj window per XCD is
// ~256KB (one j-column slab) instead of the full 4MB slice.
// adj keeps the 2-deep register pipeline (covers cold-miss latency at the
// sweep front); h (L2-resident 1KB chunks) and s2 stay 1-ahead.
// P via wave-private LDS; no barriers, no in-loop shuffles.
__global__ __launch_bounds__(64) void gat_attn_kernel(
    const float* __restrict__ adj, const float* __restrict__ att_mask,
    const __bf16* __restrict__ hF, const float* __restrict__ s1w,
    const float* __restrict__ s2w, float* __restrict__ out)
{
    __shared__ __align__(16) __bf16 p_l[16 * 72];   // [row][j], pad 72

    const int blk   = blockIdx.x;
    const int t     = blk & 7;        // XCD id
    const int r_    = blk >> 3;       // 0..255
    const int b     = r_ & 3;
    const int itile = r_ >> 2;        // 0..63
    const int bt    = b * 8 + t;
    const int irow0 = itile * 16;
    const int lane  = threadIdx.x;      // = j within tile (score phase)
    const int l15   = lane & 15;
    const int quad  = lane >> 4;

    f32x4 acc[4];
#pragma unroll
    for (int nc = 0; nc < 4; ++nc) acc[nc] = (f32x4){0.f, 0.f, 0.f, 0.f};
    float lsum[16], s1v[16];
#pragma unroll
    for (int r = 0; r < 16; ++r) {
        lsum[r] = 0.f;
        s1v[r]  = s1w[bt * N_NODES + irow0 + r];
    }

    const float*  adjrow = adj + (size_t)t * N_NODES * N_NODES
                               + (size_t)irow0 * N_NODES + lane;
    const __bf16* htb    = hF + (size_t)bt * 16 * 4096 + lane * 8;
    const float*  s2bt   = s2w + bt * N_NODES;
    __bf16* pwr = p_l + lane;                         // score write (lane = j)
    const __bf16* prd = p_l + l15 * 72 + quad * 8;    // P A-frag read

    // ---- preload: adj tiles 0,1 (2-deep); h/s2 tile 0 ----
    float  adj0[16], adj1[16];
    bf16x8 hc[8];
    float  s2c;
    {
#pragma unroll
        for (int r = 0; r < 16; ++r) {
            adj0[r] = adjrow[(size_t)r * N_NODES];
            adj1[r] = adjrow[(size_t)r * N_NODES + 64];
        }
#pragma unroll
        for (int c = 0; c < 8; ++c) hc[c] = *(const bf16x8*)(htb + c * 512);
        s2c = s2bt[lane];
    }

#pragma unroll 2
    for (int it = 0; it < 16; ++it) {
        const int jt1 = (it + 1) & 15;   // next tile (h/s2)
        const int jt2 = (it + 2) & 15;   // tile after (adj)

        // ---- prefetch: adj 2 ahead, h/s2 1 ahead ----
        float  adjn[16];
        bf16x8 hn[8];
#pragma unroll
        for (int r = 0; r < 16; ++r)
            adjn[r] = adjrow[(size_t)r * N_NODES + jt2 * 64];
        const __bf16* hp = htb + (size_t)jt1 * 4096;
#pragma unroll
        for (int c = 0; c < 8; ++c) hn[c] = *(const bf16x8*)(hp + c * 512);
        const float s2n = s2bt[jt1 * 64 + lane];

        // ---- scores for current tile (lane = j); leaky bounds e*adj in
        // [-6,~16] so exp never overflows -> no max pass needed ----
#pragma unroll
        for (int r = 0; r < 16; ++r) {
            float e = s1v[r] + s2c;
            e = fmaxf(e, 0.2f * e);
            float p = (adj0[r] > 0.f) ? __expf(e * adj0[r]) : 0.f;
            lsum[r] += p;
            pwr[r * 72] = (__bf16)p;
        }

        // ---- P -> A-frag via wave-private LDS, then 8 MFMAs ----
        bf16x8 af0 = *(const bf16x8*)(prd);
        bf16x8 af1 = *(const bf16x8*)(prd + 32);
#pragma unroll
        for (int nc = 0; nc < 4; ++nc)
            acc[nc] = __builtin_amdgcn_mfma_f32_16x16x32_bf16(af0, hc[nc], acc[nc], 0, 0, 0);
#pragma unroll
        for (int nc = 0; nc < 4; ++nc)
            acc[nc] = __builtin_amdgcn_mfma_f32_16x16x32_bf16(af1, hc[4 + nc], acc[nc], 0, 0, 0);

        // ---- shift pipelines (unroll-2 renames the copies away) ----
#pragma unroll
        for (int r = 0; r < 16; ++r) { adj0[r] = adj1[r]; adj1[r] = adjn[r]; }
#pragma unroll
        for (int c = 0; c < 8; ++c) hc[c] = hn[c];
        s2c = s2n;
    }

    // ---- epilogue: reduce lsum once, mi/ls scale + ELU + store ----
#pragma unroll
    for (int r = 0; r < 16; ++r) {
#pragma unroll
        for (int off = 32; off; off >>= 1)
            lsum[r] += __shfl_xor(lsum[r], off, 64);
    }
#pragma unroll
    for (int reg = 0; reg < 4; ++reg) {
        float ls = (quad == 0) ? lsum[reg] : (quad == 1) ? lsum[4 + reg]
                 : (quad == 2) ? lsum[8 + reg] : lsum[12 + reg];
        const int i = irow0 + quad * 4 + reg;
        float mi    = att_mask[((size_t)b * N_NODES + i) * T_DIM + t];
        float scale = mi / ls;
#pragma unroll
        for (int nc = 0; nc < 4; ++nc) {
            float v = acc[nc][reg] * scale;
            v = (v > 0.f) ? v : (__expf(v) - 1.f);
            out[((size_t)bt * N_NODES + i) * 64 + nc * 16 + l15] = v;
        }
    }
}

extern "C" void kernel_launch(void* const* d_in, const int* in_sizes, int n_in,
                              void* d_out, int out_size, void* d_ws, size_t ws_size,
                              hipStream_t stream) {
    (void)in_sizes; (void)n_in; (void)out_size; (void)ws_size;
    const float* adj      = (const float*)d_in[0];   // (T,N,N)
    const float* inp      = (const float*)d_in[1];   // (B,T,N,FI)
    const float* att_mask = (const float*)d_in[2];   // (B,N,T)
    const float* W        = (const float*)d_in[3];   // (FI,FO)
    const float* a        = (const float*)d_in[4];   // (2*FO,1)
    float* out = (float*)d_out;

    // ws: hF 4MB | s1 128KB | s2 128KB
    __bf16* hF  = (__bf16*)d_ws;
    float*  s1w = (float*)((char*)d_ws + (size_t)4 * 1024 * 1024);
    float*  s2w = s1w + 32 * N_NODES;

    gat_h_kernel<<<512, 256, 0, stream>>>(inp, W, a, att_mask, hF, s1w, s2w);
    gat_attn_kernel<<<2048, 64, 0, stream>>>(adj, att_mask, hF, s1w, s2w, out);
}